// Round 5
// baseline (8158.212 us; speedup 1.0000x reference)
//
#include <hip/hip_runtime.h>

typedef unsigned short ushort;
typedef __attribute__((ext_vector_type(8))) short short8;
typedef __attribute__((ext_vector_type(4))) float f32x4;

#define Bb 2
#define Tt 2048
#define Dd 2048
#define Hh 16
#define Mm 4096                 // B*T
#define MD 8388608u             // Mm*Dd

__device__ __forceinline__ float b2f(ushort u) {
  union { unsigned int ui; float f; } v; v.ui = ((unsigned int)u) << 16; return v.f;
}
__device__ __forceinline__ ushort f2b(float f) {
  union { float f; unsigned int u; } v; v.f = f;
  unsigned int r = (v.u + 0x7fffu + ((v.u >> 16) & 1u)) >> 16;
  return (ushort)r;
}
__device__ __forceinline__ void split3(float v, ushort& s0, ushort& s1, ushort& s2) {
  ushort a = f2b(v);        float f0 = b2f(a);
  float r1 = v - f0;        ushort b = f2b(r1);  float f1 = b2f(b);
  float r2 = r1 - f1;       ushort c = f2b(r2);
  s0 = a; s1 = b; s2 = c;
}
__device__ __forceinline__ float softplusf(float x) {
  return fmaxf(x, 0.f) + log1pf(expf(-fabsf(x)));
}

// ---------------- transpose one DxD fp32 matrix -> 3 bf16 split planes, transposed ----------------
__global__ __launch_bounds__(256) void split_transpose3(const float* __restrict__ W,
                                                        ushort* __restrict__ T0,
                                                        ushort* __restrict__ T1,
                                                        ushort* __restrict__ T2) {
  __shared__ float tile[64][68];
  int k0 = blockIdx.x << 6, n0 = blockIdx.y << 6;
  int r = threadIdx.x >> 2, c0 = (threadIdx.x & 3) << 4;
  const float* src = W + (size_t)(k0 + r) * Dd + n0 + c0;
#pragma unroll
  for (int q = 0; q < 4; ++q)
    *(float4*)&tile[r][c0 + 4 * q] = *(const float4*)(src + 4 * q);
  __syncthreads();
  ushort h0[16], h1[16], h2[16];
#pragma unroll
  for (int i = 0; i < 16; ++i) split3(tile[c0 + i][r], h0[i], h1[i], h2[i]);
  size_t o = (size_t)(n0 + r) * Dd + k0 + c0;
  *(uint4*)(T0 + o) = *(uint4*)&h0[0];  *(uint4*)(T0 + o + 8) = *(uint4*)&h0[8];
  *(uint4*)(T1 + o) = *(uint4*)&h1[0];  *(uint4*)(T1 + o + 8) = *(uint4*)&h1[8];
  *(uint4*)(T2 + o) = *(uint4*)&h2[0];  *(uint4*)(T2 + o + 8) = *(uint4*)&h2[8];
}

// ------------- 64x64-tile 6-term split-bf16 MFMA GEMM (fp32-grade): C = A(fp32) * Bt^T -------------
template <int BF16OUT>
__global__ __launch_bounds__(256) void gemm6(const float* __restrict__ A,
                                             const ushort* __restrict__ B0,
                                             const ushort* __restrict__ B1,
                                             const ushort* __restrict__ B2,
                                             void* __restrict__ CBase) {
  const int N = 2048, K = 2048;
  int m0 = blockIdx.y << 6, n0 = blockIdx.x << 6;
  __shared__ ushort As0[4096], As1[4096], As2[4096];
  __shared__ ushort Bs0[4096], Bs1[4096], Bs2[4096];
  int tid = threadIdx.x;
  int row = tid >> 2, c0 = (tid & 3) << 4;
  int sw = row & 7;
  int g0 = c0 >> 3;
  int dst0 = row * 64 + ((g0 ^ sw) << 3);
  int dst1 = row * 64 + (((g0 + 1) ^ sw) << 3);
  const float* aptr = A + (size_t)(m0 + row) * K + c0;
  const ushort* b0p = B0 + (size_t)(n0 + row) * K + c0;
  const ushort* b1p = B1 + (size_t)(n0 + row) * K + c0;
  const ushort* b2p = B2 + (size_t)(n0 + row) * K + c0;
  int lane = tid & 63, wave = tid >> 6;
  int l16 = lane & 15, quad = lane >> 4;
  int wm = (wave & 1) << 5, wn = (wave >> 1) << 5;
  f32x4 acc[2][2] = {};
  for (int k0 = 0; k0 < K; k0 += 64) {
    float av[16];
#pragma unroll
    for (int q = 0; q < 4; ++q)
      *(float4*)&av[4 * q] = *(const float4*)(aptr + k0 + 4 * q);
    ushort a0[16], a1[16], a2[16];
#pragma unroll
    for (int i = 0; i < 16; ++i) split3(av[i], a0[i], a1[i], a2[i]);
    uint4 b00 = *(const uint4*)(b0p + k0), b01 = *(const uint4*)(b0p + k0 + 8);
    uint4 b10 = *(const uint4*)(b1p + k0), b11 = *(const uint4*)(b1p + k0 + 8);
    uint4 b20 = *(const uint4*)(b2p + k0), b21 = *(const uint4*)(b2p + k0 + 8);
    *(uint4*)&As0[dst0] = *(uint4*)&a0[0];  *(uint4*)&As0[dst1] = *(uint4*)&a0[8];
    *(uint4*)&As1[dst0] = *(uint4*)&a1[0];  *(uint4*)&As1[dst1] = *(uint4*)&a1[8];
    *(uint4*)&As2[dst0] = *(uint4*)&a2[0];  *(uint4*)&As2[dst1] = *(uint4*)&a2[8];
    *(uint4*)&Bs0[dst0] = b00;  *(uint4*)&Bs0[dst1] = b01;
    *(uint4*)&Bs1[dst0] = b10;  *(uint4*)&Bs1[dst1] = b11;
    *(uint4*)&Bs2[dst0] = b20;  *(uint4*)&Bs2[dst1] = b21;
    __syncthreads();
#pragma unroll
    for (int kk = 0; kk < 2; ++kk) {
      short8 af0[2], af1[2], af2[2], bf0[2], bf1[2], bf2[2];
#pragma unroll
      for (int mi = 0; mi < 2; ++mi) {
        int rr = wm + (mi << 4) + l16;
        int g = (kk << 2) + quad;
        int idx = rr * 64 + ((g ^ (rr & 7)) << 3);
        af0[mi] = *(const short8*)&As0[idx];
        af1[mi] = *(const short8*)&As1[idx];
        af2[mi] = *(const short8*)&As2[idx];
      }
#pragma unroll
      for (int nj = 0; nj < 2; ++nj) {
        int rr = wn + (nj << 4) + l16;
        int g = (kk << 2) + quad;
        int idx = rr * 64 + ((g ^ (rr & 7)) << 3);
        bf0[nj] = *(const short8*)&Bs0[idx];
        bf1[nj] = *(const short8*)&Bs1[idx];
        bf2[nj] = *(const short8*)&Bs2[idx];
      }
#pragma unroll
      for (int mi = 0; mi < 2; ++mi)
#pragma unroll
        for (int nj = 0; nj < 2; ++nj) {
          // smallest-magnitude terms first for accuracy
          acc[mi][nj] = __builtin_amdgcn_mfma_f32_16x16x32_bf16(af2[mi], bf0[nj], acc[mi][nj], 0, 0, 0);
          acc[mi][nj] = __builtin_amdgcn_mfma_f32_16x16x32_bf16(af0[mi], bf2[nj], acc[mi][nj], 0, 0, 0);
          acc[mi][nj] = __builtin_amdgcn_mfma_f32_16x16x32_bf16(af1[mi], bf1[nj], acc[mi][nj], 0, 0, 0);
          acc[mi][nj] = __builtin_amdgcn_mfma_f32_16x16x32_bf16(af1[mi], bf0[nj], acc[mi][nj], 0, 0, 0);
          acc[mi][nj] = __builtin_amdgcn_mfma_f32_16x16x32_bf16(af0[mi], bf1[nj], acc[mi][nj], 0, 0, 0);
          acc[mi][nj] = __builtin_amdgcn_mfma_f32_16x16x32_bf16(af0[mi], bf0[nj], acc[mi][nj], 0, 0, 0);
        }
    }
    __syncthreads();
  }
#pragma unroll
  for (int mi = 0; mi < 2; ++mi)
#pragma unroll
    for (int nj = 0; nj < 2; ++nj)
#pragma unroll
      for (int r = 0; r < 4; ++r) {
        int mm = m0 + wm + (mi << 4) + (quad << 2) + r;
        int nn = n0 + wn + (nj << 4) + l16;
        float v = acc[mi][nj][r];
        if (BF16OUT)
          ((ushort*)CBase)[(size_t)mm * N + nn] = f2b(v);
        else
          ((float*)CBase)[(size_t)mm * N + nn] = v;
      }
}

// ---------------- 64x64-tile bf16-A x bf16-B GEMM (final projection), fp32 out ----------------
__global__ __launch_bounds__(256) void gemm_b16A(const ushort* __restrict__ A,
                                                 const ushort* __restrict__ Bt,
                                                 float* __restrict__ C) {
  const int N = 2048, K = 2048;
  int m0 = blockIdx.y << 6, n0 = blockIdx.x << 6;
  __shared__ ushort As[64 * 64];
  __shared__ ushort Bs[64 * 64];
  int tid = threadIdx.x;
  int row = tid >> 2, c0 = (tid & 3) << 4;
  int sw = row & 7;
  int g0 = c0 >> 3;
  int dst0 = row * 64 + ((g0 ^ sw) << 3);
  int dst1 = row * 64 + (((g0 + 1) ^ sw) << 3);
  const ushort* aptr = A + (size_t)(m0 + row) * K + c0;
  const ushort* bptr = Bt + (size_t)(n0 + row) * K + c0;
  int lane = tid & 63, wave = tid >> 6;
  int l16 = lane & 15, quad = lane >> 4;
  int wm = (wave & 1) << 5, wn = (wave >> 1) << 5;
  f32x4 acc[2][2] = {};
  for (int k0 = 0; k0 < K; k0 += 64) {
    uint4 av0 = *(const uint4*)(aptr + k0);
    uint4 av1 = *(const uint4*)(aptr + k0 + 8);
    uint4 bv0 = *(const uint4*)(bptr + k0);
    uint4 bv1 = *(const uint4*)(bptr + k0 + 8);
    *(uint4*)&As[dst0] = av0;
    *(uint4*)&As[dst1] = av1;
    *(uint4*)&Bs[dst0] = bv0;
    *(uint4*)&Bs[dst1] = bv1;
    __syncthreads();
#pragma unroll
    for (int kk = 0; kk < 2; ++kk) {
      short8 af[2], bf[2];
#pragma unroll
      for (int mi = 0; mi < 2; ++mi) {
        int rr = wm + (mi << 4) + l16;
        int g = (kk << 2) + quad;
        af[mi] = *(const short8*)&As[rr * 64 + ((g ^ (rr & 7)) << 3)];
      }
#pragma unroll
      for (int nj = 0; nj < 2; ++nj) {
        int rr = wn + (nj << 4) + l16;
        int g = (kk << 2) + quad;
        bf[nj] = *(const short8*)&Bs[rr * 64 + ((g ^ (rr & 7)) << 3)];
      }
#pragma unroll
      for (int mi = 0; mi < 2; ++mi)
#pragma unroll
        for (int nj = 0; nj < 2; ++nj)
          acc[mi][nj] = __builtin_amdgcn_mfma_f32_16x16x32_bf16(af[mi], bf[nj], acc[mi][nj], 0, 0, 0);
    }
    __syncthreads();
  }
#pragma unroll
  for (int mi = 0; mi < 2; ++mi)
#pragma unroll
    for (int nj = 0; nj < 2; ++nj)
#pragma unroll
      for (int r = 0; r < 4; ++r) {
        int mm = m0 + wm + (mi << 4) + (quad << 2) + r;
        int nn = n0 + wn + (nj << 4) + l16;
        C[(size_t)mm * N + nn] = acc[mi][nj][r];
      }
}

// ---------------- clock pre-activation: x @ W_clock (2048x16), fp32 ----------------
__global__ __launch_bounds__(64) void wclock_k(const float* __restrict__ x,
                                               const float* __restrict__ Wc,
                                               float* __restrict__ out) {
  int m = blockIdx.x, lane = threadIdx.x;
  const float* xr = x + (size_t)m * Dd;
  float acc[16];
#pragma unroll
  for (int h = 0; h < 16; ++h) acc[h] = 0.f;
  for (int k = lane; k < Dd; k += 64) {
    float xv = xr[k];
    const float* wr = Wc + k * 16;
#pragma unroll
    for (int h = 0; h < 16; ++h) acc[h] += xv * wr[h];
  }
#pragma unroll
  for (int h = 0; h < 16; ++h) {
#pragma unroll
    for (int off = 32; off; off >>= 1) acc[h] += __shfl_down(acc[h], off);
  }
  if (lane == 0) {
    float* o = out + (size_t)m * 16;
#pragma unroll
    for (int h = 0; h < 16; ++h) o[h] = acc[h];
  }
}

// ---------------- per-chunk max of p = (x@W_p) + log(clock) over 256-t chunks ----------------
__global__ __launch_bounds__(128) void pmaxchunk_k(const float* __restrict__ Pf,
                                                   const float* __restrict__ cpre,
                                                   float* __restrict__ pmaxc) {
  int bh = blockIdx.x, ch = blockIdx.y, d = threadIdx.x;
  int b = bh >> 4, h = bh & 15;
  float mx = -1e30f;
  int t0 = ch << 8;
  for (int t = t0; t < t0 + 256; ++t) {
    float pr = Pf[((size_t)(b * Tt + t)) * Dd + h * 128 + d];
    float c = softplusf(cpre[(b * Tt + t) * Hh + h]) + 1e-6f;
    mx = fmaxf(mx, pr + logf(c));
  }
  pmaxc[(size_t)(bh * 8 + ch) * 128 + d] = mx;
}

// ---------------- serial scan over t, IN PLACE ----------------
// A <- rope(q); B <- rope(k); C <- exp(clip(cumsum(gj))); D <- pe (exact!), pcs checkpoints
__global__ __launch_bounds__(128) void scan_k(float* planes,
                                              const float* __restrict__ cpre,
                                              const float* __restrict__ pmaxc,
                                              float* __restrict__ clockv,
                                              float* __restrict__ ccsv,
                                              float* __restrict__ pcs_cp) {
  int bh = blockIdx.x, b = bh >> 4, h = bh & 15, d = threadIdx.x;
  float* Qf = planes;
  float* Kf = planes + (size_t)MD;
  float* Gf = planes + 2 * (size_t)MD;
  float* Pf = planes + 3 * (size_t)MD;
  float invf = (float)exp(-((double)((d & 63) * 2) / 128.0) * log(10000.0));
  float pmax = -1e30f;
#pragma unroll
  for (int c = 0; c < 8; ++c) pmax = fmaxf(pmax, pmaxc[(size_t)(bh * 8 + c) * 128 + d]);
  float pcs = 0.f, gcs = 0.f, ccs = 0.f;
  for (int t = 0; t < Tt; ++t) {
    size_t off = ((size_t)(b * Tt + t)) * Dd + h * 128 + d;
    float qv = Qf[off], kv = Kf[off], pv = Pf[off], gv = Gf[off];
    float clock = softplusf(cpre[(b * Tt + t) * Hh + h]) + 1e-6f;
    float ang = (float)t * invf;
    float c_ = cosf(ang), s_ = sinf(ang);
    float qp = __shfl_xor(qv, 1);
    float kp = __shfl_xor(kv, 1);
    float qrot = (d & 1) ? qp : -qp;
    float krot = (d & 1) ? kp : -kp;
    float qr = qv * c_ + qrot * s_;
    float kr = kv * c_ + krot * s_;
    float p = pv + logf(clock);
    float pe = expf(p - pmax);
    if ((t & 31) == 0) pcs_cp[((size_t)bh * 64 + (t >> 5)) * 128 + d] = pcs;
    pcs = pcs + pe;
    float gj = -softplusf(gv) * clock;
    gcs += gj;
    float e = expf(fminf(fmaxf(gcs, -50.f), 40.f));
    ccs += clock;
    Qf[off] = qr;
    Kf[off] = kr;
    Gf[off] = e;
    Pf[off] = pe;
    if (d == 0) {
      clockv[bh * Tt + t] = clock;
      ccsv[bh * Tt + t] = ccs;
    }
  }
}

// ---------------- fp32 flash attention, q/k reconstructed during staging ----------------
__global__ __launch_bounds__(256) void attn32_k(const float* __restrict__ planes,
                                                const ushort* __restrict__ Vb,
                                                const float* __restrict__ clockv,
                                                const float* __restrict__ ccsv,
                                                const float* __restrict__ pcs_cp,
                                                ushort* __restrict__ attnout) {
  __shared__ float smem[16384];          // exactly 64 KB
  float* Qs = smem;                      // 32*384 fp32, swizzled
  float* Ks = smem + 32 * 384;           // 32*128 fp32, swizzled; later aliased:
  float* Pt = Ks;                        //   Pt 32*33 fp32
  ushort* Vs = (ushort*)(Ks + 1056);     //   Vs 32*128 bf16

  int tid = threadIdx.x;
  int qt0 = blockIdx.x << 5;
  int bh = blockIdx.y, b = bh >> 4, h = bh & 15;
  const float* Qf = planes;
  const float* Kf = planes + (size_t)MD;
  const float* Ef = planes + 2 * (size_t)MD;   // e = exp(clip(gcs))
  const float* Pe = planes + 3 * (size_t)MD;   // pe (exact)
  size_t pbase = ((size_t)b * Tt) * Dd + h * 128;
  const ushort* vbase = Vb + pbase;

  // ---- pass 1: stage Q tile: slot1 <- qr (divided later), slot2 <- qr*e, slot3 <- qr/ccs ----
  for (int g = tid; g < 1024; g += 256) {
    int r = g >> 5, c4g = g & 31;
    size_t off = pbase + (size_t)(qt0 + r) * Dd + (c4g << 2);
    float4 q4 = *(const float4*)(Qf + off);
    float4 e4 = *(const float4*)(Ef + off);
    float ccs = ccsv[bh * Tt + qt0 + r];
    int sw = (r >> 2) & 7;
    float4 o2, o3;
    o2.x = q4.x * e4.x; o2.y = q4.y * e4.y; o2.z = q4.z * e4.z; o2.w = q4.w * e4.w;
    o3.x = q4.x / ccs; o3.y = q4.y / ccs; o3.z = q4.z / ccs; o3.w = q4.w / ccs;
    *(float4*)&Qs[r * 384 + ((c4g ^ sw) << 2)] = q4;
    *(float4*)&Qs[r * 384 + (((32 + c4g) ^ sw) << 2)] = o2;
    *(float4*)&Qs[r * 384 + (((64 + c4g) ^ sw) << 2)] = o3;
  }
  __syncthreads();
  // ---- pass 2: per-column sequential pcs replay (bit-exact vs scan), divide q1 slot ----
  if (tid < 128) {
    int d = tid;
    float pcs = pcs_cp[((size_t)bh * 64 + (qt0 >> 5)) * 128 + d];
    int gd = d >> 2, dl = d & 3;
    for (int r = 0; r < 32; ++r) {
      pcs = pcs + Pe[pbase + (size_t)(qt0 + r) * Dd + d];
      int addr = r * 384 + ((gd ^ ((r >> 2) & 7)) << 2) + dl;
      Qs[addr] = Qs[addr] / (pcs + 1e-8f);
    }
  }

  int rgrp = tid >> 4, cgrp = tid & 15;
  int r0 = rgrp << 1, c0 = cgrp << 1, vc0 = cgrp << 3;
  int swq = (r0 >> 2) & 7, swk = (c0 >> 2) & 7;
  float o[2][8], mi_[2], li[2];
#pragma unroll
  for (int i = 0; i < 2; ++i) {
    mi_[i] = -1e30f; li[i] = 0.f;
#pragma unroll
    for (int j = 0; j < 8; ++j) o[i][j] = 0.f;
  }
  const float scl = 0.05103103630798287f;  // 1/sqrt(384)

  for (int st = 0; st < 64; ++st) {
    int s0 = st << 5;
    float sa[2][2] = {};
    for (int cd = 0; cd < 3; ++cd) {
      __syncthreads();  // previous readers of Ks/Pt/Vs done (also orders pass-2 writes)
      // ---- stage K chunk with reconstruction ----
      for (int g = tid; g < 1024; g += 256) {
        int r = g >> 5, c4g = g & 31;
        int s = s0 + r;
        size_t off = pbase + (size_t)s * Dd + (c4g << 2);
        float4 k4 = *(const float4*)(Kf + off);
        float4 ov;
        if (cd == 0) {
          float4 p4 = *(const float4*)(Pe + off);
          ov.x = k4.x * p4.x; ov.y = k4.y * p4.y; ov.z = k4.z * p4.z; ov.w = k4.w * p4.w;
        } else if (cd == 1) {
          float4 e4 = *(const float4*)(Ef + off);
          ov.x = k4.x / (e4.x + 1e-8f); ov.y = k4.y / (e4.y + 1e-8f);
          ov.z = k4.z / (e4.z + 1e-8f); ov.w = k4.w / (e4.w + 1e-8f);
        } else {
          float ck = clockv[bh * Tt + s];
          ov.x = k4.x * ck; ov.y = k4.y * ck; ov.z = k4.z * ck; ov.w = k4.w * ck;
        }
        *(float4*)&Ks[r * 128 + ((c4g ^ ((r >> 2) & 7)) << 2)] = ov;
      }
      __syncthreads();
      int qgb = cd << 5;
#pragma unroll 4
      for (int kk4 = 0; kk4 < 32; ++kk4) {
        float4 aq[2], bk[2];
#pragma unroll
        for (int i = 0; i < 2; ++i)
          aq[i] = *(const float4*)&Qs[(r0 + i) * 384 + (((qgb + kk4) ^ swq) << 2)];
#pragma unroll
        for (int j = 0; j < 2; ++j)
          bk[j] = *(const float4*)&Ks[(c0 + j) * 128 + ((kk4 ^ swk) << 2)];
#pragma unroll
        for (int i = 0; i < 2; ++i)
#pragma unroll
          for (int j = 0; j < 2; ++j)
            sa[i][j] += aq[i].x * bk[j].x + aq[i].y * bk[j].y + aq[i].z * bk[j].z + aq[i].w * bk[j].w;
      }
    }
    __syncthreads();  // all score reads of Ks done; safe to write Pt / Vs (alias)
    // ---- online softmax ----
#pragma unroll
    for (int i = 0; i < 2; ++i) {
      float mx = -1e30f;
#pragma unroll
      for (int j = 0; j < 2; ++j) { sa[i][j] *= scl; mx = fmaxf(mx, sa[i][j]); }
#pragma unroll
      for (int msk = 1; msk < 16; msk <<= 1) mx = fmaxf(mx, __shfl_xor(mx, msk));
      float mn = fmaxf(mi_[i], mx);
      float alpha = expf(mi_[i] - mn);
      float p0 = expf(sa[i][0] - mn);
      float p1 = expf(sa[i][1] - mn);
      float rs = p0 + p1;
#pragma unroll
      for (int msk = 1; msk < 16; msk <<= 1) rs += __shfl_xor(rs, msk);
      li[i] = li[i] * alpha + rs;
      mi_[i] = mn;
#pragma unroll
      for (int j = 0; j < 8; ++j) o[i][j] *= alpha;
      Pt[(r0 + i) * 33 + c0] = p0;
      Pt[(r0 + i) * 33 + c0 + 1] = p1;
    }
    // ---- stage V tile (bf16) ----
    {
      int r = tid >> 3, cb = (tid & 7) << 4;
      const ushort* vsrc = vbase + (size_t)(s0 + r) * Dd + cb;
      *(uint4*)&Vs[r * 128 + cb] = *(const uint4*)vsrc;
      *(uint4*)&Vs[r * 128 + cb + 8] = *(const uint4*)(vsrc + 8);
    }
    __syncthreads();  // Pt + Vs visible
#pragma unroll 2
    for (int c = 0; c < 32; ++c) {
      float pi0 = Pt[r0 * 33 + c];
      float pi1 = Pt[(r0 + 1) * 33 + c];
      uint4 vv = *(const uint4*)&Vs[c * 128 + vc0];
      float vf[8];
      {
        union { unsigned int u; float f; } t0_, t1_;
        unsigned int us[4] = {vv.x, vv.y, vv.z, vv.w};
#pragma unroll
        for (int q = 0; q < 4; ++q) {
          t0_.u = us[q] << 16;          vf[2 * q] = t0_.f;
          t1_.u = us[q] & 0xffff0000u;  vf[2 * q + 1] = t1_.f;
        }
      }
#pragma unroll
      for (int j = 0; j < 8; ++j) {
        o[0][j] += pi0 * vf[j];
        o[1][j] += pi1 * vf[j];
      }
    }
  }
#pragma unroll
  for (int i = 0; i < 2; ++i) {
    float inv = 1.f / li[i];
    int t = qt0 + r0 + i;
    ushort* orow = attnout + ((size_t)(b * Tt + t)) * Dd + h * 128 + vc0;
#pragma unroll
    for (int j = 0; j < 8; ++j) orow[j] = f2b(o[i][j] * inv);
  }
}

extern "C" void kernel_launch(void* const* d_in, const int* in_sizes, int n_in,
                              void* d_out, int out_size, void* d_ws, size_t ws_size,
                              hipStream_t stream) {
  const float* x = (const float*)d_in[0];
  const float* Wq = (const float*)d_in[1];
  const float* Wk = (const float*)d_in[2];
  const float* Wv = (const float*)d_in[3];
  const float* Wg = (const float*)d_in[4];
  const float* Wp = (const float*)d_in[5];
  const float* Wclk = (const float*)d_in[6];
  const float* Wc = (const float*)d_in[7];

  // ---- workspace layout (~178 MiB) ----
  float* planes = (float*)d_ws;                       // 4 * MD fp32: qr | kr | e | pe
  float* Aq = planes;
  float* Bk = planes + (size_t)MD;
  float* Ce = planes + 2 * (size_t)MD;
  float* Dp = planes + 3 * (size_t)MD;
  ushort* Vb = (ushort*)(planes + 4 * (size_t)MD);    // MD bf16
  float* cpre = (float*)(Vb + (size_t)MD);            // 65536
  float* clockv = cpre + 65536;                       // 65536
  float* ccsv = clockv + 65536;                       // 65536
  float* pmaxc = ccsv + 65536;                        // 32768
  float* pcs_cp = pmaxc + 32768;                      // 32*64*128 = 262144
  ushort* Wt0 = (ushort*)(pcs_cp + 262144);           // 3 x Dd*Dd bf16 (projection phase)
  ushort* Wt1 = Wt0 + (size_t)Dd * Dd;
  ushort* Wt2 = Wt1 + (size_t)Dd * Dd;
  ushort* attnout = Wt0;                              // reuse Wt region (dead after projections)
  ushort* WcT0 = (ushort*)Ce;                         // post-attention: reuse e-plane for Wc^T
  ushort* WcT1 = WcT0 + (size_t)Dd * Dd;
  ushort* WcT2 = WcT1 + (size_t)Dd * Dd;

  size_t needed = (size_t)((char*)(Wt2 + (size_t)Dd * Dd) - (char*)d_ws);
  if (ws_size < needed) return;  // diagnostic: absmax ~= 4.69 => ws too small

  dim3 tg(Dd / 64, Dd / 64), gg(Dd / 64, Mm / 64);

  // Q, K, G, P projections (fp32 out, 6-term split-bf16 MFMA = fp32-grade)
  split_transpose3<<<tg, 256, 0, stream>>>(Wq, Wt0, Wt1, Wt2);
  gemm6<0><<<gg, 256, 0, stream>>>(x, Wt0, Wt1, Wt2, (void*)Aq);
  split_transpose3<<<tg, 256, 0, stream>>>(Wk, Wt0, Wt1, Wt2);
  gemm6<0><<<gg, 256, 0, stream>>>(x, Wt0, Wt1, Wt2, (void*)Bk);
  split_transpose3<<<tg, 256, 0, stream>>>(Wg, Wt0, Wt1, Wt2);
  gemm6<0><<<gg, 256, 0, stream>>>(x, Wt0, Wt1, Wt2, (void*)Ce);
  split_transpose3<<<tg, 256, 0, stream>>>(Wp, Wt0, Wt1, Wt2);
  gemm6<0><<<gg, 256, 0, stream>>>(x, Wt0, Wt1, Wt2, (void*)Dp);
  // V projection (bf16 out)
  split_transpose3<<<tg, 256, 0, stream>>>(Wv, Wt0, Wt1, Wt2);
  gemm6<1><<<gg, 256, 0, stream>>>(x, Wt0, Wt1, Wt2, (void*)Vb);

  // clock pre-activation, chunked p_max, serial scan (in-place)
  wclock_k<<<dim3(Mm), dim3(64), 0, stream>>>(x, Wclk, cpre);
  pmaxchunk_k<<<dim3(Bb * Hh, 8), dim3(128), 0, stream>>>(Dp, cpre, pmaxc);
  scan_k<<<dim3(Bb * Hh), dim3(128), 0, stream>>>(planes, cpre, pmaxc, clockv, ccsv, pcs_cp);

  // flash attention -> attnout (bf16, in dead Wt region)
  attn32_k<<<dim3(Tt / 32, Bb * Hh), dim3(256), 0, stream>>>(planes, Vb, clockv, ccsv, pcs_cp, attnout);

  // Wc^T (into dead e-plane), then final GEMM -> fp32 d_out
  split_transpose3<<<tg, 256, 0, stream>>>(Wc, WcT0, WcT1, WcT2);
  gemm_b16A<<<gg, 256, 0, stream>>>(attnout, WcT0, (float*)d_out);
}